// Round 2
// baseline (703.005 us; speedup 1.0000x reference)
//
#include <hip/hip_runtime.h>
#include <cstddef>

// ContextWindowAttention: B=8192 windows, N=49 tokens, C=128, H=4, D=32.
// v3: kill the softmax latency bomb (128 scalar bias/mask loads/thread -> 16 float4
// loads from m-major padded tables with -1e30 in the n-pad), double-buffer all weight
// fragment streams, mt-outer softmax with prefetch. LDS stays 32KB.

#define MFMA16 __builtin_amdgcn_mfma_f32_16x16x32_bf16

typedef float f32x4 __attribute__((ext_vector_type(4)));
typedef __bf16 bf16x8 __attribute__((ext_vector_type(8)));
typedef __bf16 bf16x4 __attribute__((ext_vector_type(4)));

constexpr int NTOK = 49;
constexpr int CDIM = 128;
constexpr int NWIN = 1024;
constexpr int NB = 8192;
constexpr float SCALE_F = 0.17677669529663687f;  // 32^-0.5

// Swizzled byte offsets (16B blocks XORed with row bits -> spread banks).
__device__ __forceinline__ int sw128(int row, int col) {  // [rows][128] bf16
  return (row << 8) + ((((col >> 3) ^ row) & 15) << 4) + ((col & 7) << 1);
}
__device__ __forceinline__ int sw64(int row, int col) {  // [rows][64] bf16
  return (row << 7) + ((((col >> 3) ^ (row >> 1)) & 7) << 4) + ((col & 7) << 1);
}
// Per-wave P scratch: [64 m][32 n] bf16 (4KB), XOR swizzle for b128 reads.
__device__ __forceinline__ int swp(int m, int nl) {
  return (m << 6) + ((((nl >> 3) ^ (m >> 1)) & 3) << 4) + ((nl & 7) << 1);
}

// ---------------- prepack: weights -> bf16 B-fragment order, m-major padded bias ----
// wFrag: [mat(4)][frag(32)][lane(64)][8] bf16, frag = nt*4+ks.
// Fragment element j of lane (q4,li): W[k = ks*32+q4*8+j][n = nt*16+li].
// biasM[h][m][n64]: bias[h][m][n] for n<49, 0 in the pad (n 49..63). 16B-aligned rows.
__global__ void prepack_kernel(const float* __restrict__ Wq, const float* __restrict__ Wkv,
                               const float* __restrict__ Wp, const float* __restrict__ bias_table,
                               const int* __restrict__ rel_idx,
                               unsigned short* __restrict__ wFrag, float* __restrict__ biasM) {
  int t = blockIdx.x * 256 + threadIdx.x;  // grid 96*256 = 24576
  if (t < 8192) {
    const int mat = t >> 11;  // 0..3
    const int g = t & 2047;
    const int frag = g >> 6, lane = g & 63;
    const int nt = frag >> 2, ks = frag & 3;
    const int li = lane & 15, q4 = lane >> 4;
    const int n = nt * 16 + li;
    bf16x8 tmp;
#pragma unroll
    for (int j = 0; j < 8; ++j) {
      const int k = ks * 32 + q4 * 8 + j;
      float v;
      if (mat == 0) v = Wq[k * 128 + n];
      else if (mat == 1) v = Wkv[k * 256 + n];
      else if (mat == 2) v = Wkv[k * 256 + 128 + n];
      else v = Wp[k * 128 + n];
      tmp[j] = (__bf16)v;
    }
    *(bf16x8*)(wFrag + (size_t)t * 8) = tmp;
  } else {
    const int tb = t - 8192;  // 0..12543 covers [4][49][64]
    if (tb < 4 * 49 * 64) {
      const int h = tb / 3136;
      const int rem = tb - h * 3136;
      const int m = rem >> 6, n = rem & 63;
      float v = 0.f;
      if (n < NTOK) v = bias_table[rel_idx[m * 49 + n] * 4 + h];
      biasM[tb] = v;
    }
  }
}

// maskM[w][m][n64] = mask[w][m][n] for n<49, -1e30 in the pad. Coalesced both sides.
__global__ void maskM_kernel(const float* __restrict__ mask, float* __restrict__ maskM) {
  __shared__ float sm[2401];
  const int w = blockIdx.x;
  for (int i = threadIdx.x; i < 2401; i += 256) sm[i] = mask[(size_t)w * 2401 + i];
  __syncthreads();
  for (int i = threadIdx.x; i < 3136; i += 256) {
    const int m = i >> 6, n = i & 63;
    maskM[(size_t)w * 3136 + i] = (n < NTOK) ? sm[m * 49 + n] : -1e30f;
  }
}

template <bool PADMASK>
__global__ __launch_bounds__(256, 4) void attn_kernel(
    const float* __restrict__ x, const float* __restrict__ y, const float* __restrict__ maskp,
    const float* __restrict__ bq, const float* __restrict__ bkv, const float* __restrict__ bp,
    const unsigned short* __restrict__ wFrag, const float* __restrict__ biasM,
    float* __restrict__ out) {
  // buf0 @0     (16KB): Q[64][128] -> per-wave 4KB P scratch -> Z[64][128]
  // buf1 @16384 (16KB): K[64][128] -> Vt[128][64]
  __shared__ __align__(16) unsigned char lds[32768];
  const int tid = threadIdx.x;
  const int w = tid >> 6;
  const int lane = tid & 63;
  const int li = lane & 15;
  const int q4 = lane >> 4;
  const int b = blockIdx.x;
  const int mh = w >> 1;  // token-half
  const int nh = w & 1;   // channel-half

  // ---- A-fragments of X and Y (rows >= 49 zeroed) ----
  bf16x8 ax[2][4], ay[2][4];
#pragma unroll
  for (int t = 0; t < 2; ++t) {
    const int mrow = mh * 32 + t * 16 + li;
    const bool mv = mrow < NTOK;
    const float* xr = x + ((size_t)b * NTOK + (mv ? mrow : 0)) * CDIM;
    const float* yr = y + ((size_t)b * NTOK + (mv ? mrow : 0)) * CDIM;
#pragma unroll
    for (int ks = 0; ks < 4; ++ks) {
      const int c0 = ks * 32 + q4 * 8;
      float4 a0 = *(const float4*)(xr + c0);
      float4 a1 = *(const float4*)(xr + c0 + 4);
      float4 b0 = *(const float4*)(yr + c0);
      float4 b1 = *(const float4*)(yr + c0 + 4);
      if (!mv) {
        a0.x = a0.y = a0.z = a0.w = 0.f; a1.x = a1.y = a1.z = a1.w = 0.f;
        b0.x = b0.y = b0.z = b0.w = 0.f; b1.x = b1.y = b1.z = b1.w = 0.f;
      }
      bf16x8 ta, tb;
      ta[0] = (__bf16)a0.x; ta[1] = (__bf16)a0.y; ta[2] = (__bf16)a0.z; ta[3] = (__bf16)a0.w;
      ta[4] = (__bf16)a1.x; ta[5] = (__bf16)a1.y; ta[6] = (__bf16)a1.z; ta[7] = (__bf16)a1.w;
      tb[0] = (__bf16)b0.x; tb[1] = (__bf16)b0.y; tb[2] = (__bf16)b0.z; tb[3] = (__bf16)b0.w;
      tb[4] = (__bf16)b1.x; tb[5] = (__bf16)b1.y; tb[6] = (__bf16)b1.z; tb[7] = (__bf16)b1.w;
      ax[t][ks] = ta;
      ay[t][ks] = tb;
    }
  }

  const unsigned short* wq = wFrag + 0 * 16384 + nh * 8192;
  const unsigned short* wk = wFrag + 1 * 16384 + nh * 8192;
  const unsigned short* wv = wFrag + 2 * 16384 + nh * 8192;
  const unsigned short* wp = wFrag + 3 * 16384 + nh * 8192;

  auto ldw = [&](const unsigned short* base, int ntl, bf16x8* dst) {
#pragma unroll
    for (int ks = 0; ks < 4; ++ks)
      dst[ks] = *(const bf16x8*)(base + (ntl * 4 + ks) * 512 + lane * 8);
  };

  // ---- Phase 1: Q,K,V projections, 12-step loop, double-buffered weight frags.
  // Q,K swapped (MFMA(W,X) = (XW)^T -> lane holds 4 consecutive channels, b64 write);
  // V unswapped (lane holds 4 consecutive tokens -> b64 write in Vt layout).
  bf16x8 wfb[2][4];
  bf16x4 vpk[2][4];
  ldw(wq, 0, wfb[0]);
#pragma unroll
  for (int s = 0; s < 12; ++s) {
    if (s < 11) {
      const int nn = s + 1;
      ldw(nn < 4 ? wq : (nn < 8 ? wk : wv), nn & 3, wfb[nn & 1]);
    }
    const int mat = s >> 2, ntl = s & 3;
    const bf16x8* wf = wfb[s & 1];
    if (mat < 2) {
      const int ch0 = nh * 64 + ntl * 16 + q4 * 4;
      const float4 b4 = *(const float4*)((mat == 0 ? bq : bkv) + ch0);
      const int ldsoff = (mat == 0) ? 0 : 16384;
#pragma unroll
      for (int t = 0; t < 2; ++t) {
        const bf16x8* af = (mat == 0) ? &ax[t][0] : &ay[t][0];
        f32x4 acc = {0.f, 0.f, 0.f, 0.f};
#pragma unroll
        for (int ks = 0; ks < 4; ++ks) acc = MFMA16(wf[ks], af[ks], acc, 0, 0, 0);
        const int tok = mh * 32 + t * 16 + li;
        bf16x4 pv;
        pv[0] = (__bf16)(acc[0] + b4.x); pv[1] = (__bf16)(acc[1] + b4.y);
        pv[2] = (__bf16)(acc[2] + b4.z); pv[3] = (__bf16)(acc[3] + b4.w);
        *(bf16x4*)(lds + ldsoff + sw128(tok, ch0)) = pv;
      }
    } else {
      const int nV = nh * 64 + ntl * 16 + li;
      const float bvv = bkv[128 + nV];
#pragma unroll
      for (int t = 0; t < 2; ++t) {
        f32x4 acc = {0.f, 0.f, 0.f, 0.f};
#pragma unroll
        for (int ks = 0; ks < 4; ++ks) acc = MFMA16(ay[t][ks], wf[ks], acc, 0, 0, 0);
        bf16x4 vv4;
        vv4[0] = (__bf16)(acc[0] + bvv); vv4[1] = (__bf16)(acc[1] + bvv);
        vv4[2] = (__bf16)(acc[2] + bvv); vv4[3] = (__bf16)(acc[3] + bvv);
        vpk[t][ntl] = vv4;
      }
    }
  }
  __syncthreads();  // #1: Q,K ready

  // ---- Phase 2a: wave = head. S^T = MFMA(K,Q): elem r -> (n = nt*16+q4*4+r, m = mt*16+li).
  const int h = w;
  unsigned char* const pbase = lds + w * 4096;  // per-wave P scratch in buf0
  bf16x8 aqf[4], bkf[4];
#pragma unroll
  for (int mt = 0; mt < 4; ++mt)
    aqf[mt] = *(const bf16x8*)(lds + sw128(mt * 16 + li, h * 32 + q4 * 8));
#pragma unroll
  for (int nt = 0; nt < 4; ++nt)
    bkf[nt] = *(const bf16x8*)(lds + 16384 + sw128(nt * 16 + li, h * 32 + q4 * 8));

  const float* __restrict__ biasw = biasM + h * 3136;
  const float* __restrict__ maskw =
      PADMASK ? maskp + (size_t)(b & (NWIN - 1)) * 3136 : maskp + (size_t)(b & (NWIN - 1)) * 2401;

  // combined bias+mask float4 loads for one mt (4 vectors)
  auto ldbm = [&](int mt, f32x4* dst) {
    const int m = mt * 16 + li;
    const int mm = (m < NTOK ? m : 0);
#pragma unroll
    for (int nt = 0; nt < 4; ++nt) {
      const int nc = nt * 16 + q4 * 4;
      const f32x4 bv = *(const f32x4*)(biasw + mm * 64 + nc);
      f32x4 mv;
      if (PADMASK) {
        mv = *(const f32x4*)(maskw + mm * 64 + nc);
      } else {
#pragma unroll
        for (int r = 0; r < 4; ++r) {
          const int n = nc + r;
          mv[r] = (n < NTOK) ? maskw[mm * 49 + n] : -1e30f;
        }
      }
      dst[nt] = bv + mv;
    }
  };

  f32x4 bmv[2][4];
  ldbm(0, bmv[0]);  // in flight across barrier #2 drain
  __syncthreads();  // #2: all Q/K LDS reads done -> buf0/buf1 reusable

  // Vt -> buf1 (b64 writes; overlaps softmax below)
#pragma unroll
  for (int ntl = 0; ntl < 4; ++ntl) {
    const int nV = nh * 64 + ntl * 16 + li;
#pragma unroll
    for (int t = 0; t < 2; ++t)
      *(bf16x4*)(lds + 16384 + sw64(nV, mh * 32 + t * 16 + q4 * 4)) = vpk[t][ntl];
  }

  // mt-outer: 4 MFMAs -> softmax(mt); prefetch next mt's bias+mask before the MFMAs.
  float inv4[4];
  bf16x4 pHi[4][2];  // chunk1 (n 32..63), kept in regs until mid-PV
  const f32x4 zz = {0.f, 0.f, 0.f, 0.f};
#pragma unroll
  for (int mt = 0; mt < 4; ++mt) {
    if (mt < 3) ldbm(mt + 1, bmv[(mt + 1) & 1]);
    f32x4 s4[4];
#pragma unroll
    for (int nt = 0; nt < 4; ++nt) s4[nt] = MFMA16(bkf[nt], aqf[mt], zz, 0, 0, 0);
    const f32x4* bm = bmv[mt & 1];
    float vv[4][4];
    float mx = -3.0e38f;
#pragma unroll
    for (int nt = 0; nt < 4; ++nt)
#pragma unroll
      for (int r = 0; r < 4; ++r) {
        const float tv = fmaf(SCALE_F, s4[nt][r], bm[nt][r]);  // pad n has -1e30 baked in
        vv[nt][r] = tv;
        mx = fmaxf(mx, tv);
      }
    mx = fmaxf(mx, __shfl_xor(mx, 16));
    mx = fmaxf(mx, __shfl_xor(mx, 32));
    float sm = 0.f;
#pragma unroll
    for (int nt = 0; nt < 4; ++nt)
#pragma unroll
      for (int r = 0; r < 4; ++r) {
        const float e = __expf(vv[nt][r] - mx);
        vv[nt][r] = e;
        sm += e;
      }
    sm += __shfl_xor(sm, 16);
    sm += __shfl_xor(sm, 32);
    inv4[mt] = __builtin_amdgcn_rcpf(sm);
    bf16x4 p0, p1;
    p0[0] = (__bf16)vv[0][0]; p0[1] = (__bf16)vv[0][1];
    p0[2] = (__bf16)vv[0][2]; p0[3] = (__bf16)vv[0][3];
    p1[0] = (__bf16)vv[1][0]; p1[1] = (__bf16)vv[1][1];
    p1[2] = (__bf16)vv[1][2]; p1[3] = (__bf16)vv[1][3];
    *(bf16x4*)(pbase + swp(mt * 16 + li, q4 * 4)) = p0;       // n 0..15 block
    *(bf16x4*)(pbase + swp(mt * 16 + li, 16 + q4 * 4)) = p1;  // n 16..31 block
    bf16x4 h0, h1;
    h0[0] = (__bf16)vv[2][0]; h0[1] = (__bf16)vv[2][1];
    h0[2] = (__bf16)vv[2][2]; h0[3] = (__bf16)vv[2][3];
    h1[0] = (__bf16)vv[3][0]; h1[1] = (__bf16)vv[3][1];
    h1[2] = (__bf16)vv[3][2]; h1[3] = (__bf16)vv[3][3];
    pHi[mt][0] = h0;
    pHi[mt][1] = h1;
  }
  __syncthreads();  // #3: Vt ready

  // ---- Phase 2b: O^T = MFMA(V^T, P), K-dim chunked 2x32 through the 4KB scratch ----
  bf16x8 bv2[2][2];
#pragma unroll
  for (int cht = 0; cht < 2; ++cht)
#pragma unroll
    for (int ksn = 0; ksn < 2; ++ksn)
      bv2[cht][ksn] =
          *(const bf16x8*)(lds + 16384 + sw64(h * 32 + cht * 16 + li, ksn * 32 + q4 * 8));
  f32x4 o[2][4];
  {
    bf16x8 ap[4];
#pragma unroll
    for (int mt = 0; mt < 4; ++mt)
      ap[mt] = *(const bf16x8*)(pbase + swp(mt * 16 + li, q4 * 8));
#pragma unroll
    for (int cht = 0; cht < 2; ++cht)
#pragma unroll
      for (int mt = 0; mt < 4; ++mt) o[cht][mt] = MFMA16(bv2[cht][0], ap[mt], zz, 0, 0, 0);
    // overwrite scratch with chunk 1 (same-wave in-order DS makes the WAR safe)
#pragma unroll
    for (int mt = 0; mt < 4; ++mt) {
      *(bf16x4*)(pbase + swp(mt * 16 + li, q4 * 4)) = pHi[mt][0];
      *(bf16x4*)(pbase + swp(mt * 16 + li, 16 + q4 * 4)) = pHi[mt][1];
    }
#pragma unroll
    for (int mt = 0; mt < 4; ++mt)
      ap[mt] = *(const bf16x8*)(pbase + swp(mt * 16 + li, q4 * 8));
#pragma unroll
    for (int cht = 0; cht < 2; ++cht)
#pragma unroll
      for (int mt = 0; mt < 4; ++mt)
        o[cht][mt] = MFMA16(bv2[cht][1], ap[mt], o[cht][mt], 0, 0, 0);
  }
  __syncthreads();  // #4: all PV reads done -> buf0 reusable for Z

  // Z[tok][chan], deferred softmax normalization here (inv is per-col m = li ✓)
#pragma unroll
  for (int cht = 0; cht < 2; ++cht)
#pragma unroll
    for (int mt = 0; mt < 4; ++mt) {
      bf16x4 zv;
      zv[0] = (__bf16)(o[cht][mt][0] * inv4[mt]);
      zv[1] = (__bf16)(o[cht][mt][1] * inv4[mt]);
      zv[2] = (__bf16)(o[cht][mt][2] * inv4[mt]);
      zv[3] = (__bf16)(o[cht][mt][3] * inv4[mt]);
      *(bf16x4*)(lds + sw128(mt * 16 + li, h * 32 + cht * 16 + q4 * 4)) = zv;
    }
  ldw(wp, 0, wfb[0]);  // prefetch Wp frag 0 under the Z-write + barrier drain
  __syncthreads();     // #5: Z ready

  // ---- Phase 3: out = Z @ Wp + bp, SWAPPED -> float4 stores; wp double-buffered ----
  bf16x8 az[2][4];
#pragma unroll
  for (int t = 0; t < 2; ++t)
#pragma unroll
    for (int ks = 0; ks < 4; ++ks)
      az[t][ks] = *(const bf16x8*)(lds + sw128(mh * 32 + t * 16 + li, ks * 32 + q4 * 8));
#pragma unroll
  for (int ntl = 0; ntl < 4; ++ntl) {
    if (ntl < 3) ldw(wp, ntl + 1, wfb[(ntl + 1) & 1]);
    const bf16x8* wf = wfb[ntl & 1];
    const int ch0 = nh * 64 + ntl * 16 + q4 * 4;
    const float4 b4 = *(const float4*)(bp + ch0);
#pragma unroll
    for (int t = 0; t < 2; ++t) {
      f32x4 acc = {0.f, 0.f, 0.f, 0.f};
#pragma unroll
      for (int ks = 0; ks < 4; ++ks) acc = MFMA16(wf[ks], az[t][ks], acc, 0, 0, 0);
      const int tok = mh * 32 + t * 16 + li;
      if (tok < NTOK) {
        float4 st;
        st.x = acc[0] + b4.x; st.y = acc[1] + b4.y;
        st.z = acc[2] + b4.z; st.w = acc[3] + b4.w;
        *(float4*)(out + ((size_t)b * NTOK + tok) * CDIM + ch0) = st;
      }
    }
  }
}

extern "C" void kernel_launch(void* const* d_in, const int* in_sizes, int n_in, void* d_out,
                              int out_size, void* d_ws, size_t ws_size, hipStream_t stream) {
  const float* x = (const float*)d_in[0];
  const float* y = (const float*)d_in[1];
  const float* mask = (const float*)d_in[2];
  const float* Wq = (const float*)d_in[3];
  const float* bq = (const float*)d_in[4];
  const float* Wkv = (const float*)d_in[5];
  const float* bkv = (const float*)d_in[6];
  const float* bt = (const float*)d_in[7];
  const float* Wp = (const float*)d_in[8];
  const float* bp = (const float*)d_in[9];
  const int* rel = (const int*)d_in[10];
  float* out = (float*)d_out;

  // ws: 128KB fragment-ordered weights + biasM[4][49][64] f32 + (optional) maskM[1024][49][64]
  unsigned short* wFrag = (unsigned short*)d_ws;
  float* biasM = (float*)((char*)d_ws + 131072);
  float* maskM = (float*)((char*)d_ws + 181248);
  const size_t needM = 181248 + (size_t)NWIN * 3136 * sizeof(float);

  prepack_kernel<<<96, 256, 0, stream>>>(Wq, Wkv, Wp, bt, rel, wFrag, biasM);
  if (ws_size >= needM) {
    maskM_kernel<<<NWIN, 256, 0, stream>>>(mask, maskM);
    attn_kernel<true><<<NB, 256, 0, stream>>>(x, y, maskM, bq, bkv, bp, wFrag, biasM, out);
  } else {
    // fallback: scalar mask reads (uncoalesced but correct)
    attn_kernel<false><<<NB, 256, 0, stream>>>(x, y, mask, bq, bkv, bp, wFrag, biasM, out);
  }
}

// Round 3
// 638.354 us; speedup vs baseline: 1.1013x; 1.1013x over previous
//
#include <hip/hip_runtime.h>
#include <cstddef>

// ContextWindowAttention: B=8192 windows, N=49 tokens, C=128, H=4, D=32.
// v4: attack L2 latency/traffic. Pre-summed bias+mask table (one f32x4 stream, -1e30
// pad baked in), depth-2 weight prefetch (3 rotating buffers), V-projection moved after
// barrier #1 to flatten register peak, launch_bounds(256,3) to stop remat-to-64-VGPR,
// setprio around attention MFMA clusters. LDS stays 32KB.

#define MFMA16 __builtin_amdgcn_mfma_f32_16x16x32_bf16

typedef float f32x4 __attribute__((ext_vector_type(4)));
typedef __bf16 bf16x8 __attribute__((ext_vector_type(8)));
typedef __bf16 bf16x4 __attribute__((ext_vector_type(4)));

constexpr int NTOK = 49;
constexpr int CDIM = 128;
constexpr int NWIN = 1024;
constexpr int NB = 8192;
constexpr float SCALE_F = 0.17677669529663687f;  // 32^-0.5

// Swizzled byte offsets (16B blocks XORed with row bits -> spread banks).
__device__ __forceinline__ int sw128(int row, int col) {  // [rows][128] bf16
  return (row << 8) + ((((col >> 3) ^ row) & 15) << 4) + ((col & 7) << 1);
}
__device__ __forceinline__ int sw64(int row, int col) {  // [rows][64] bf16
  return (row << 7) + ((((col >> 3) ^ (row >> 1)) & 7) << 4) + ((col & 7) << 1);
}
// Per-wave P scratch: [64 m][32 n] bf16 (4KB), XOR swizzle for b128 reads.
__device__ __forceinline__ int swp(int m, int nl) {
  return (m << 6) + ((((nl >> 3) ^ (m >> 1)) & 3) << 4) + ((nl & 7) << 1);
}

// ---------------- prepack: weights -> bf16 B-fragment order + biasM fallback ----------
// wFrag: [mat(4)][frag(32)][lane(64)][8] bf16, frag = nt*4+ks.
// Fragment element j of lane (q4,li): W[k = ks*32+q4*8+j][n = nt*16+li].
// biasM[h][m][n64] (fallback path only): bias for n<49, 0 in pad.
__global__ void prepack_kernel(const float* __restrict__ Wq, const float* __restrict__ Wkv,
                               const float* __restrict__ Wp, const float* __restrict__ bias_table,
                               const int* __restrict__ rel_idx,
                               unsigned short* __restrict__ wFrag, float* __restrict__ biasM) {
  int t = blockIdx.x * 256 + threadIdx.x;  // grid 96*256 = 24576
  if (t < 8192) {
    const int mat = t >> 11;  // 0..3
    const int g = t & 2047;
    const int frag = g >> 6, lane = g & 63;
    const int nt = frag >> 2, ks = frag & 3;
    const int li = lane & 15, q4 = lane >> 4;
    const int n = nt * 16 + li;
    bf16x8 tmp;
#pragma unroll
    for (int j = 0; j < 8; ++j) {
      const int k = ks * 32 + q4 * 8 + j;
      float v;
      if (mat == 0) v = Wq[k * 128 + n];
      else if (mat == 1) v = Wkv[k * 256 + n];
      else if (mat == 2) v = Wkv[k * 256 + 128 + n];
      else v = Wp[k * 128 + n];
      tmp[j] = (__bf16)v;
    }
    *(bf16x8*)(wFrag + (size_t)t * 8) = tmp;
  } else {
    const int tb = t - 8192;  // covers [4][49][64]
    if (tb < 4 * 49 * 64) {
      const int h = tb / 3136;
      const int rem = tb - h * 3136;
      const int m = rem >> 6, n = rem & 63;
      float v = 0.f;
      if (n < NTOK) v = bias_table[rel_idx[m * 49 + n] * 4 + h];
      biasM[tb] = v;
    }
  }
}

// bmSum[w][h][m][n64] = bias[h][m][n] + mask[w][m][n] for n<49, -1e30 in the pad.
__global__ void bmsum_kernel(const float* __restrict__ mask, const float* __restrict__ bias_table,
                             const int* __restrict__ rel_idx, float* __restrict__ bmSum) {
  __shared__ float smk[2401];
  __shared__ int ri[2401];
  __shared__ float bt[169 * 4];
  const int w = blockIdx.x;
  for (int i = threadIdx.x; i < 2401; i += 256) {
    smk[i] = mask[(size_t)w * 2401 + i];
    ri[i] = rel_idx[i];
  }
  for (int i = threadIdx.x; i < 676; i += 256) bt[i] = bias_table[i];
  __syncthreads();
  for (int i = threadIdx.x; i < 3136; i += 256) {
    const int m = i >> 6, n = i & 63;
    const bool valid = (n < NTOK);
    const int mi = m * 49 + (valid ? n : 0);
    const float base = smk[mi];
    const int r = ri[mi];
#pragma unroll
    for (int h = 0; h < 4; ++h) {
      bmSum[((size_t)w * 4 + h) * 3136 + i] = valid ? (bt[r * 4 + h] + base) : -1e30f;
    }
  }
}

template <bool PRESUM>
__global__ __launch_bounds__(256, 3) void attn_kernel(
    const float* __restrict__ x, const float* __restrict__ y, const float* __restrict__ maskp,
    const float* __restrict__ bq, const float* __restrict__ bkv, const float* __restrict__ bp,
    const unsigned short* __restrict__ wFrag, const float* __restrict__ biasM,
    float* __restrict__ out) {
  // buf0 @0     (16KB): Q[64][128] -> per-wave 4KB P scratch -> Z[64][128]
  // buf1 @16384 (16KB): K[64][128] -> Vt[128][64]
  __shared__ __align__(16) unsigned char lds[32768];
  const int tid = threadIdx.x;
  const int w = tid >> 6;
  const int lane = tid & 63;
  const int li = lane & 15;
  const int q4 = lane >> 4;
  const int b = blockIdx.x;
  const int mh = w >> 1;  // token-half
  const int nh = w & 1;   // channel-half

  // ---- A-fragments of X and Y (pad rows clamp to row 0; finite garbage is masked
  // downstream: S-pad killed by -1e30 table, O-pad rows never stored) ----
  bf16x8 ax[2][4], ay[2][4];
#pragma unroll
  for (int t = 0; t < 2; ++t) {
    const int mrow = mh * 32 + t * 16 + li;
    const int mm = mrow < NTOK ? mrow : 0;
    const float* xr = x + ((size_t)b * NTOK + mm) * CDIM;
    const float* yr = y + ((size_t)b * NTOK + mm) * CDIM;
#pragma unroll
    for (int ks = 0; ks < 4; ++ks) {
      const int c0 = ks * 32 + q4 * 8;
      const float4 a0 = *(const float4*)(xr + c0);
      const float4 a1 = *(const float4*)(xr + c0 + 4);
      const float4 b0 = *(const float4*)(yr + c0);
      const float4 b1 = *(const float4*)(yr + c0 + 4);
      bf16x8 ta, tb;
      ta[0] = (__bf16)a0.x; ta[1] = (__bf16)a0.y; ta[2] = (__bf16)a0.z; ta[3] = (__bf16)a0.w;
      ta[4] = (__bf16)a1.x; ta[5] = (__bf16)a1.y; ta[6] = (__bf16)a1.z; ta[7] = (__bf16)a1.w;
      tb[0] = (__bf16)b0.x; tb[1] = (__bf16)b0.y; tb[2] = (__bf16)b0.z; tb[3] = (__bf16)b0.w;
      tb[4] = (__bf16)b1.x; tb[5] = (__bf16)b1.y; tb[6] = (__bf16)b1.z; tb[7] = (__bf16)b1.w;
      ax[t][ks] = ta;
      ay[t][ks] = tb;
    }
  }

  const unsigned short* wq = wFrag + 0 * 16384 + nh * 8192;
  const unsigned short* wk = wFrag + 1 * 16384 + nh * 8192;
  const unsigned short* wv = wFrag + 2 * 16384 + nh * 8192;
  const unsigned short* wp = wFrag + 3 * 16384 + nh * 8192;
  const unsigned short* mats01[2] = {wq, wk};

  auto ldw = [&](const unsigned short* base, int ntl, bf16x8* dst) {
#pragma unroll
    for (int ks = 0; ks < 4; ++ks)
      dst[ks] = *(const bf16x8*)(base + (ntl * 4 + ks) * 512 + lane * 8);
  };

  // ---- Phase 1: Q,K projections (8 steps), depth-2 weight prefetch (3 buffers).
  // Swapped MFMA(W,X) = (XW)^T -> lane holds 4 consecutive channels, b64 LDS write.
  bf16x8 wfb[3][4];
  ldw(wq, 0, wfb[0]);
  ldw(wq, 1, wfb[1]);
#pragma unroll
  for (int s = 0; s < 8; ++s) {
    if (s < 6) {
      const int nn = s + 2;
      ldw(mats01[nn >> 2], nn & 3, wfb[nn % 3]);
    }
    const int mat = s >> 2, ntl = s & 3;
    const bf16x8* wf = wfb[s % 3];
    const int ch0 = nh * 64 + ntl * 16 + q4 * 4;
    const float4 b4 = *(const float4*)((mat == 0 ? bq : bkv) + ch0);
    const int ldsoff = (mat == 0) ? 0 : 16384;
#pragma unroll
    for (int t = 0; t < 2; ++t) {
      const bf16x8* af = (mat == 0) ? &ax[t][0] : &ay[t][0];
      f32x4 acc = {0.f, 0.f, 0.f, 0.f};
#pragma unroll
      for (int ks = 0; ks < 4; ++ks) acc = MFMA16(wf[ks], af[ks], acc, 0, 0, 0);
      const int tok = mh * 32 + t * 16 + li;
      bf16x4 pv;
      pv[0] = (__bf16)(acc[0] + b4.x); pv[1] = (__bf16)(acc[1] + b4.y);
      pv[2] = (__bf16)(acc[2] + b4.z); pv[3] = (__bf16)(acc[3] + b4.w);
      *(bf16x4*)(lds + ldsoff + sw128(tok, ch0)) = pv;
    }
  }
  ldw(wv, 0, wfb[0]);  // V weights in flight across the barrier
  ldw(wv, 1, wfb[1]);
  __syncthreads();  // #1: Q,K ready

  // ---- Q/K fragment reads first (latency hidden under V MFMAs) ----
  const int h = w;  // wave = head
  unsigned char* const pbase = lds + w * 4096;  // per-wave P scratch in buf0
  bf16x8 aqf[4], bkf[4];
#pragma unroll
  for (int mt = 0; mt < 4; ++mt)
    aqf[mt] = *(const bf16x8*)(lds + sw128(mt * 16 + li, h * 32 + q4 * 8));
#pragma unroll
  for (int nt = 0; nt < 4; ++nt)
    bkf[nt] = *(const bf16x8*)(lds + 16384 + sw128(nt * 16 + li, h * 32 + q4 * 8));

  // ---- V projection (unswapped: lane holds 4 consecutive tokens -> Vt layout) ----
  bf16x4 vpk[2][4];
#pragma unroll
  for (int v = 0; v < 4; ++v) {
    if (v < 2) ldw(wv, v + 2, wfb[(v + 2) % 3]);
    const bf16x8* wf = wfb[v % 3];
    const int nV = nh * 64 + v * 16 + li;
    const float bvv = bkv[128 + nV];
#pragma unroll
    for (int t = 0; t < 2; ++t) {
      f32x4 acc = {0.f, 0.f, 0.f, 0.f};
#pragma unroll
      for (int ks = 0; ks < 4; ++ks) acc = MFMA16(ay[t][ks], wf[ks], acc, 0, 0, 0);
      bf16x4 vv4;
      vv4[0] = (__bf16)(acc[0] + bvv); vv4[1] = (__bf16)(acc[1] + bvv);
      vv4[2] = (__bf16)(acc[2] + bvv); vv4[3] = (__bf16)(acc[3] + bvv);
      vpk[t][v] = vv4;
    }
  }

  // ---- bias+mask pointers; one pre-summed f32x4 stream when PRESUM ----
  const float* __restrict__ bmw =
      PRESUM ? maskp + ((size_t)(b & (NWIN - 1)) * 4 + h) * 3136 : nullptr;
  const float* __restrict__ biasw = biasM + h * 3136;
  const float* __restrict__ maskw =
      PRESUM ? nullptr : maskp + (size_t)(b & (NWIN - 1)) * 2401;

  auto ldbm = [&](int mt, f32x4* dst) {
    const int m = mt * 16 + li;
    const int mm = (m < NTOK ? m : 0);
#pragma unroll
    for (int nt = 0; nt < 4; ++nt) {
      const int nc = nt * 16 + q4 * 4;
      if (PRESUM) {
        dst[nt] = *(const f32x4*)(bmw + mm * 64 + nc);
      } else {
        const f32x4 bv = *(const f32x4*)(biasw + mm * 64 + nc);
        f32x4 mv;
#pragma unroll
        for (int r = 0; r < 4; ++r) {
          const int n = nc + r;
          mv[r] = (n < NTOK) ? maskw[mm * 49 + n] : -1e30f;
        }
        dst[nt] = bv + mv;
      }
    }
  };

  f32x4 bmv[2][4];
  ldbm(0, bmv[0]);  // in flight across barrier #2 drain
  __syncthreads();  // #2: all Q/K LDS reads done -> buf0/buf1 reusable

  // Vt -> buf1 (b64 writes; overlaps softmax below)
#pragma unroll
  for (int ntl = 0; ntl < 4; ++ntl) {
    const int nV = nh * 64 + ntl * 16 + li;
#pragma unroll
    for (int t = 0; t < 2; ++t)
      *(bf16x4*)(lds + 16384 + sw64(nV, mh * 32 + t * 16 + q4 * 4)) = vpk[t][ntl];
  }

  // mt-outer: 4 QK MFMAs -> softmax(mt); prefetch next mt's bias+mask first.
  // S^T = MFMA(K,Q): elem r -> (n = nt*16+q4*4+r, m = mt*16+li).
  float inv4[4];
  bf16x4 pHi[4][2];  // chunk1 (n 32..63), kept in regs until mid-PV
  const f32x4 zz = {0.f, 0.f, 0.f, 0.f};
#pragma unroll
  for (int mt = 0; mt < 4; ++mt) {
    if (mt < 3) ldbm(mt + 1, bmv[(mt + 1) & 1]);
    f32x4 s4[4];
    __builtin_amdgcn_s_setprio(1);
#pragma unroll
    for (int nt = 0; nt < 4; ++nt) s4[nt] = MFMA16(bkf[nt], aqf[mt], zz, 0, 0, 0);
    __builtin_amdgcn_s_setprio(0);
    const f32x4* bm = bmv[mt & 1];
    float vv[4][4];
    float mx = -3.0e38f;
#pragma unroll
    for (int nt = 0; nt < 4; ++nt)
#pragma unroll
      for (int r = 0; r < 4; ++r) {
        const float tv = fmaf(SCALE_F, s4[nt][r], bm[nt][r]);  // pad n has -1e30 baked in
        vv[nt][r] = tv;
        mx = fmaxf(mx, tv);
      }
    mx = fmaxf(mx, __shfl_xor(mx, 16));
    mx = fmaxf(mx, __shfl_xor(mx, 32));
    float sm = 0.f;
#pragma unroll
    for (int nt = 0; nt < 4; ++nt)
#pragma unroll
      for (int r = 0; r < 4; ++r) {
        const float e = __expf(vv[nt][r] - mx);
        vv[nt][r] = e;
        sm += e;
      }
    sm += __shfl_xor(sm, 16);
    sm += __shfl_xor(sm, 32);
    inv4[mt] = __builtin_amdgcn_rcpf(sm);
    bf16x4 p0, p1;
    p0[0] = (__bf16)vv[0][0]; p0[1] = (__bf16)vv[0][1];
    p0[2] = (__bf16)vv[0][2]; p0[3] = (__bf16)vv[0][3];
    p1[0] = (__bf16)vv[1][0]; p1[1] = (__bf16)vv[1][1];
    p1[2] = (__bf16)vv[1][2]; p1[3] = (__bf16)vv[1][3];
    *(bf16x4*)(pbase + swp(mt * 16 + li, q4 * 4)) = p0;       // n 0..15 block
    *(bf16x4*)(pbase + swp(mt * 16 + li, 16 + q4 * 4)) = p1;  // n 16..31 block
    bf16x4 h0, h1;
    h0[0] = (__bf16)vv[2][0]; h0[1] = (__bf16)vv[2][1];
    h0[2] = (__bf16)vv[2][2]; h0[3] = (__bf16)vv[2][3];
    h1[0] = (__bf16)vv[3][0]; h1[1] = (__bf16)vv[3][1];
    h1[2] = (__bf16)vv[3][2]; h1[3] = (__bf16)vv[3][3];
    pHi[mt][0] = h0;
    pHi[mt][1] = h1;
  }
  __syncthreads();  // #3: Vt ready

  // ---- Phase 2b: O^T = MFMA(V^T, P), K-dim chunked 2x32 through the 4KB scratch ----
  bf16x8 bv2[2][2];
#pragma unroll
  for (int cht = 0; cht < 2; ++cht)
#pragma unroll
    for (int ksn = 0; ksn < 2; ++ksn)
      bv2[cht][ksn] =
          *(const bf16x8*)(lds + 16384 + sw64(h * 32 + cht * 16 + li, ksn * 32 + q4 * 8));
  f32x4 o[2][4];
  {
    bf16x8 ap[4];
#pragma unroll
    for (int mt = 0; mt < 4; ++mt)
      ap[mt] = *(const bf16x8*)(pbase + swp(mt * 16 + li, q4 * 8));
    __builtin_amdgcn_s_setprio(1);
#pragma unroll
    for (int cht = 0; cht < 2; ++cht)
#pragma unroll
      for (int mt = 0; mt < 4; ++mt) o[cht][mt] = MFMA16(bv2[cht][0], ap[mt], zz, 0, 0, 0);
    __builtin_amdgcn_s_setprio(0);
    // overwrite scratch with chunk 1 (same-wave in-order DS makes the WAR safe)
#pragma unroll
    for (int mt = 0; mt < 4; ++mt) {
      *(bf16x4*)(pbase + swp(mt * 16 + li, q4 * 4)) = pHi[mt][0];
      *(bf16x4*)(pbase + swp(mt * 16 + li, 16 + q4 * 4)) = pHi[mt][1];
    }
#pragma unroll
    for (int mt = 0; mt < 4; ++mt)
      ap[mt] = *(const bf16x8*)(pbase + swp(mt * 16 + li, q4 * 8));
    __builtin_amdgcn_s_setprio(1);
#pragma unroll
    for (int cht = 0; cht < 2; ++cht)
#pragma unroll
      for (int mt = 0; mt < 4; ++mt)
        o[cht][mt] = MFMA16(bv2[cht][1], ap[mt], o[cht][mt], 0, 0, 0);
    __builtin_amdgcn_s_setprio(0);
  }
  __syncthreads();  // #4: all PV reads done -> buf0 reusable for Z

  // Z[tok][chan], deferred softmax normalization here (inv is per-col m = li ✓)
#pragma unroll
  for (int cht = 0; cht < 2; ++cht)
#pragma unroll
    for (int mt = 0; mt < 4; ++mt) {
      bf16x4 zv;
      zv[0] = (__bf16)(o[cht][mt][0] * inv4[mt]);
      zv[1] = (__bf16)(o[cht][mt][1] * inv4[mt]);
      zv[2] = (__bf16)(o[cht][mt][2] * inv4[mt]);
      zv[3] = (__bf16)(o[cht][mt][3] * inv4[mt]);
      *(bf16x4*)(lds + sw128(mt * 16 + li, h * 32 + cht * 16 + q4 * 4)) = zv;
    }
  ldw(wp, 0, wfb[0]);  // Wp frags 0,1 in flight across the barrier
  ldw(wp, 1, wfb[1]);
  __syncthreads();  // #5: Z ready

  // ---- Phase 3: out = Z @ Wp + bp, SWAPPED -> float4 stores; depth-2 prefetch ----
  bf16x8 az[2][4];
#pragma unroll
  for (int t = 0; t < 2; ++t)
#pragma unroll
    for (int ks = 0; ks < 4; ++ks)
      az[t][ks] = *(const bf16x8*)(lds + sw128(mh * 32 + t * 16 + li, ks * 32 + q4 * 8));
#pragma unroll
  for (int ntl = 0; ntl < 4; ++ntl) {
    if (ntl < 2) ldw(wp, ntl + 2, wfb[(ntl + 2) % 3]);
    const bf16x8* wf = wfb[ntl % 3];
    const int ch0 = nh * 64 + ntl * 16 + q4 * 4;
    const float4 b4 = *(const float4*)(bp + ch0);
#pragma unroll
    for (int t = 0; t < 2; ++t) {
      f32x4 acc = {0.f, 0.f, 0.f, 0.f};
#pragma unroll
      for (int ks = 0; ks < 4; ++ks) acc = MFMA16(wf[ks], az[t][ks], acc, 0, 0, 0);
      const int tok = mh * 32 + t * 16 + li;
      if (tok < NTOK) {
        float4 st;
        st.x = acc[0] + b4.x; st.y = acc[1] + b4.y;
        st.z = acc[2] + b4.z; st.w = acc[3] + b4.w;
        *(float4*)(out + ((size_t)b * NTOK + tok) * CDIM + ch0) = st;
      }
    }
  }
}

extern "C" void kernel_launch(void* const* d_in, const int* in_sizes, int n_in, void* d_out,
                              int out_size, void* d_ws, size_t ws_size, hipStream_t stream) {
  const float* x = (const float*)d_in[0];
  const float* y = (const float*)d_in[1];
  const float* mask = (const float*)d_in[2];
  const float* Wq = (const float*)d_in[3];
  const float* bq = (const float*)d_in[4];
  const float* Wkv = (const float*)d_in[5];
  const float* bkv = (const float*)d_in[6];
  const float* bt = (const float*)d_in[7];
  const float* Wp = (const float*)d_in[8];
  const float* bp = (const float*)d_in[9];
  const int* rel = (const int*)d_in[10];
  float* out = (float*)d_out;

  // ws: 128KB wFrag + biasM[4][49][64] f32 (fallback) + bmSum[1024][4][49][64] f32
  unsigned short* wFrag = (unsigned short*)d_ws;
  float* biasM = (float*)((char*)d_ws + 131072);
  float* bmSum = (float*)((char*)d_ws + 181248);
  const size_t needS = 181248 + (size_t)NWIN * 4 * 3136 * sizeof(float);

  prepack_kernel<<<96, 256, 0, stream>>>(Wq, Wkv, Wp, bt, rel, wFrag, biasM);
  if (ws_size >= needS) {
    bmsum_kernel<<<NWIN, 256, 0, stream>>>(mask, bt, rel, bmSum);
    attn_kernel<true><<<NB, 256, 0, stream>>>(x, y, bmSum, bq, bkv, bp, wFrag, biasM, out);
  } else {
    // fallback: biasM table + scalar mask reads (uncoalesced but correct)
    attn_kernel<false><<<NB, 256, 0, stream>>>(x, y, mask, bq, bkv, bp, wFrag, biasM, out);
  }
}